// Round 1
// baseline (3971.219 us; speedup 1.0000x reference)
//
#include <hip/hip_runtime.h>
#include <cstdint>

// ---------------- constants ----------------
#define NTOK   4096       // 16 imgs * 256 patches
#define CDIM   768
#define NHID   3072
#define NHEADS 12

typedef int i32x4 __attribute__((ext_vector_type(4)));

__device__ __forceinline__ float4 ld4(const float* p){ return *(const float4*)(p); }

__device__ __forceinline__ float gelu_f(float x){
  float x3 = x*x*x;
  return 0.5f*x*(1.0f + tanhf(0.7978845608028654f*(x + 0.044715f*x3)));
}

// ---------------- block-wide reduce (256 threads / 4 waves) ----------------
template<bool ISMAX>
__device__ __forceinline__ float block_reduce(float v, float* red){
  #pragma unroll
  for (int o = 32; o > 0; o >>= 1){
    float w = __shfl_down(v, o);
    v = ISMAX ? fmaxf(v, w) : (v + w);
  }
  int wid = threadIdx.x >> 6;
  if ((threadIdx.x & 63) == 0) red[wid] = v;
  __syncthreads();
  float r = ISMAX ? fmaxf(fmaxf(red[0], red[1]), fmaxf(red[2], red[3]))
                  : (red[0] + red[1] + red[2] + red[3]);
  __syncthreads();
  return r;
}

// ---------------- weight quantization ----------------
// 48 layers: layer = blk*4 + type; type 0=qkv(2304x768) 1=proj(768x768) 2=fc1(3072x768) 3=fc2(768x3072)
__device__ __forceinline__ const float* layer_base(int type, int blk,
    const float* wqkv, const float* wproj, const float* wfc1, const float* wfc2,
    long* n_out, long* qoff_out)
{
  switch (type){
    case 0:  *n_out = 2304L*768; *qoff_out = 0;       return wqkv  + (long)blk*2304*768;
    case 1:  *n_out = 768L*768;  *qoff_out = 1769472; return wproj + (long)blk*768*768;
    case 2:  *n_out = 3072L*768; *qoff_out = 2359296; return wfc1  + (long)blk*3072*768;
    default: *n_out = 768L*3072; *qoff_out = 4718592; return wfc2  + (long)blk*768*3072;
  }
}

__global__ __launch_bounds__(256) void k_wabs_reduce(
  const float* __restrict__ wqkv, const float* __restrict__ wproj,
  const float* __restrict__ wfc1, const float* __restrict__ wfc2,
  float* __restrict__ acc)
{
  __shared__ float red[4];
  int layer = blockIdx.y, blk = layer >> 2, type = layer & 3;
  long n, qoff;
  const float* base = layer_base(type, blk, wqkv, wproj, wfc1, wfc2, &n, &qoff);
  long i0 = ((long)blockIdx.x*256 + threadIdx.x)*8;
  float s = 0.f;
  if (i0 < n){
    float4 a = ld4(base+i0), b = ld4(base+i0+4);
    s = fabsf(a.x)+fabsf(a.y)+fabsf(a.z)+fabsf(a.w)
      + fabsf(b.x)+fabsf(b.y)+fabsf(b.z)+fabsf(b.w);
  }
  s = block_reduce<false>(s, red);
  if (threadIdx.x == 0 && s != 0.f) atomicAdd(&acc[layer], s);
}

__global__ void k_wscale(const float* __restrict__ acc, float* __restrict__ wsc){
  int l = threadIdx.x;
  if (l < 48){
    const float cnt[4] = {2304.f*768.f, 768.f*768.f, 3072.f*768.f, 768.f*3072.f};
    wsc[l] = acc[l]/cnt[l & 3] + 1e-5f;
  }
}

__global__ __launch_bounds__(256) void k_wquant_write(
  const float* __restrict__ wqkv, const float* __restrict__ wproj,
  const float* __restrict__ wfc1, const float* __restrict__ wfc2,
  const float* __restrict__ wsc, signed char* __restrict__ wq)
{
  int layer = blockIdx.y, blk = layer >> 2, type = layer & 3;
  long n, qoff;
  const float* base = layer_base(type, blk, wqkv, wproj, wfc1, wfc2, &n, &qoff);
  long i0 = ((long)blockIdx.x*256 + threadIdx.x)*8;
  if (i0 >= n) return;
  signed char* dst = wq + (long)blk*7077888 + qoff;
  float ws = wsc[layer];
  float4 a = ld4(base+i0), b = ld4(base+i0+4);
  float v[8] = {a.x,a.y,a.z,a.w,b.x,b.y,b.z,b.w};
  long pk;
  char* pc = (char*)&pk;
  #pragma unroll
  for (int e = 0; e < 8; e++){
    float r = rintf(v[e] / ws);            // precise div + round-half-even == jnp.round
    r = fminf(1.f, fmaxf(-1.f, r));
    pc[e] = (char)(int)r;
  }
  *(long*)(dst + i0) = pk;
}

// ---------------- patchify / unpatchify ----------------
__global__ __launch_bounds__(256) void k_patchify(const float* __restrict__ x, float* __restrict__ xp){
  int idx = blockIdx.x*256 + threadIdx.x;   // over 4096*768
  int col = idx % 768, row = idx / 768;
  int bb = row >> 8, pr = row & 255, ph = pr >> 4, pw = pr & 15;
  int c = col >> 8, rem = col & 255, ii = rem >> 4, jj = rem & 15;
  xp[idx] = x[(((long)(bb*3 + c) << 8) + (ph<<4) + ii)*256 + (pw<<4) + jj];
}

__global__ __launch_bounds__(256) void k_unpatchify(const float* __restrict__ H, float* __restrict__ out){
  int idx = blockIdx.x*256 + threadIdx.x;   // over 16*3*256*256
  int xc = idx & 255;
  int y  = (idx >> 8) & 255;
  int bc = idx >> 16;
  int bb = bc / 3, c = bc % 3;
  int row = (bb << 8) + ((y >> 4) << 4) + (xc >> 4);
  int col = (c << 8) + ((y & 15) << 4) + (xc & 15);
  out[idx] = H[(long)row*768 + col];
}

// ---------------- time embedding (tiny) ----------------
__global__ __launch_bounds__(256) void k_time_full(
  const float* __restrict__ tt, const float* __restrict__ w1, const float* __restrict__ b1,
  const float* __restrict__ w2, const float* __restrict__ b2,
  float* __restrict__ temb, float* __restrict__ silu)
{
  __shared__ float emb[768];
  __shared__ float h1[768];
  int b = blockIdx.x, tid = threadIdx.x;
  float tv = tt[b];
  for (int i = tid; i < 768; i += 256){
    int idx = (i < 384) ? i : (i - 384);
    float fr = expf(-9.210340371976184f * (float)idx / 383.f);
    float a = tv * fr;
    emb[i] = (i < 384) ? sinf(a) : cosf(a);
  }
  __syncthreads();
  for (int o = tid; o < 768; o += 256){
    const float* wr = w1 + (long)o*768;
    float s = b1[o];
    for (int d = 0; d < 768; d += 4){
      float4 w4 = ld4(wr+d);
      s += w4.x*emb[d] + w4.y*emb[d+1] + w4.z*emb[d+2] + w4.w*emb[d+3];
    }
    h1[o] = gelu_f(s);
  }
  __syncthreads();
  for (int o = tid; o < 768; o += 256){
    const float* wr = w2 + (long)o*768;
    float s = b2[o];
    for (int d = 0; d < 768; d += 4){
      float4 w4 = ld4(wr+d);
      s += w4.x*h1[d] + w4.y*h1[d+1] + w4.z*h1[d+2] + w4.w*h1[d+3];
    }
    temb[b*768 + o] = s;
    silu[b*768 + o] = s / (1.f + expf(-s));
  }
}

// ---------------- adaLN modulation for all layers ----------------
// grid (chunk 0..11, layer 0..11); mod[l][b][r] = silu(temb[b]) . ada_w[l][r] + ada_b[l][r]
__global__ __launch_bounds__(256) void k_mod_all(
  const float* __restrict__ silu, const float* __restrict__ wada, const float* __restrict__ bada,
  float* __restrict__ mod)
{
  __shared__ float ss[12288];     // 16 x 768
  int l = blockIdx.y, ch = blockIdx.x, tid = threadIdx.x;
  for (int i = tid; i < 12288; i += 256) ss[i] = silu[i];
  __syncthreads();
  int r = (ch << 8) + tid;
  const float* wr = wada + ((long)l*3072 + r)*768;
  float accv[16];
  #pragma unroll
  for (int b2 = 0; b2 < 16; b2++) accv[b2] = 0.f;
  for (int d = 0; d < 768; d += 4){
    float4 w4 = ld4(wr+d);
    #pragma unroll
    for (int b2 = 0; b2 < 16; b2++){
      float4 s4 = *(const float4*)&ss[b2*768 + d];
      accv[b2] += w4.x*s4.x + w4.y*s4.y + w4.z*s4.z + w4.w*s4.w;
    }
  }
  float bb = bada[(long)l*3072 + r];
  #pragma unroll
  for (int b2 = 0; b2 < 16; b2++)
    mod[((long)l*16 + b2)*3072 + r] = accv[b2] + bb;
}

// ---------------- rmsnorm + modulate + int8 quantize ----------------
// mod_off: 0 for (shift1,scale1), 1536 for (shift2,scale2)
__global__ __launch_bounds__(256) void k_rmsnorm_mod_quant(
  const float* __restrict__ Z, const float* __restrict__ nw,
  const float* __restrict__ mod, int mod_off,
  signed char* __restrict__ XQ, float* __restrict__ XS)
{
  __shared__ float red[4];
  int row = blockIdx.x, tid = threadIdx.x;
  int b = row >> 8;
  const float* zr = Z + (long)row*768;
  const float* mo = mod + (long)b*3072 + mod_off;
  float v[3]; float ss = 0.f;
  #pragma unroll
  for (int k = 0; k < 3; k++){ v[k] = zr[tid + k*256]; ss += v[k]*v[k]; }
  ss = block_reduce<false>(ss, red);
  float rms = rsqrtf(ss*(1.f/768.f) + 1e-6f);
  float h[3]; float amax = 0.f;
  #pragma unroll
  for (int k = 0; k < 3; k++){
    int c = tid + k*256;
    h[k] = v[k]*rms*nw[c]*(1.f + mo[768 + c]) + mo[c];
    amax = fmaxf(amax, fabsf(h[k]));
  }
  amax = block_reduce<true>(amax, red);
  float xs = 127.f / fmaxf(amax, 1e-5f);
  #pragma unroll
  for (int k = 0; k < 3; k++){
    int q = (int)rintf(h[k]*xs);
    q = min(127, max(-128, q));
    XQ[(long)row*768 + tid + k*256] = (signed char)q;
  }
  if (tid == 0) XS[row] = xs;
}

// ---------------- plain row quantize (attn-out 768 / mlp 3072) ----------------
template<int W>
__global__ __launch_bounds__(256) void k_quant_rows(
  const float* __restrict__ X, signed char* __restrict__ XQ, float* __restrict__ XS)
{
  __shared__ float red[4];
  int row = blockIdx.x, tid = threadIdx.x;
  const float* xr = X + (long)row*W;
  constexpr int E = W/256;
  float v[E]; float amax = 0.f;
  #pragma unroll
  for (int k = 0; k < E; k++){ v[k] = xr[tid + k*256]; amax = fmaxf(amax, fabsf(v[k])); }
  amax = block_reduce<true>(amax, red);
  float xs = 127.f / fmaxf(amax, 1e-5f);
  #pragma unroll
  for (int k = 0; k < E; k++){
    int q = (int)rintf(v[k]*xs);
    q = min(127, max(-128, q));
    XQ[(long)row*W + tid + k*256] = (signed char)q;
  }
  if (tid == 0) XS[row] = xs;
}

__global__ __launch_bounds__(256) void k_rmsnorm_final(
  const float* __restrict__ Z, const float* __restrict__ nw, float* __restrict__ Y)
{
  __shared__ float red[4];
  int row = blockIdx.x, tid = threadIdx.x;
  const float* zr = Z + (long)row*768;
  float v[3]; float ss = 0.f;
  #pragma unroll
  for (int k = 0; k < 3; k++){ v[k] = zr[tid + k*256]; ss += v[k]*v[k]; }
  ss = block_reduce<false>(ss, red);
  float rms = rsqrtf(ss*(1.f/768.f) + 1e-6f);
  #pragma unroll
  for (int k = 0; k < 3; k++){
    int c = tid + k*256;
    Y[(long)row*768 + c] = v[k]*rms*nw[c];
  }
}

// ---------------- int8 x ternary GEMM via MFMA (m97 structure) ----------------
// C[M,N] = (A[M,K]i8 @ B[N,K]i8^T) * wsc / xs[row];  128x128 tile, BK=64, 4 waves
#define GLDS16(g, l) __builtin_amdgcn_global_load_lds( \
    (const __attribute__((address_space(1))) void*)(g), \
    (__attribute__((address_space(3))) void*)(l), 16, 0, 0)

template<int EPI>  // 0=store, 1=residual-add, 2=gelu-store
__global__ __launch_bounds__(256, 2) void k_gemm_i8(
  const signed char* __restrict__ A, const signed char* __restrict__ Bw,
  const float* __restrict__ xs, const float* __restrict__ wsc_p,
  float* __restrict__ C, int N, int K)
{
  __shared__ signed char As[8192];
  __shared__ signed char Bs[8192];
  const int tid = threadIdx.x;
  const int w = tid >> 6, l = tid & 63;
  const int m0 = blockIdx.y << 7, n0 = blockIdx.x << 7;
  const float wsc = wsc_p[0];
  i32x4 acc[4][4] = {};
  const int srow = (w << 5) + (l >> 2);
  const int scol = (l & 3) << 4;
  const signed char* Ag0 = A  + (long)(m0 + srow)*K + scol;
  const signed char* Bg0 = Bw + (long)(n0 + srow)*K + scol;
  const long row16 = 16L*K;
  signed char* lA0 = As + (w << 11);
  signed char* lA1 = lA0 + 1024;
  signed char* lB0 = Bs + (w << 11);
  signed char* lB1 = lB0 + 1024;
  const int fr = l & 15;
  const int fc = (l >> 4) << 4;
  const int wm = (w >> 1) << 6, wn = (w & 1) << 6;

  for (int kt = 0; kt < K; kt += 64){
    __syncthreads();
    GLDS16(Ag0 + kt, lA0);
    GLDS16(Ag0 + row16 + kt, lA1);
    GLDS16(Bg0 + kt, lB0);
    GLDS16(Bg0 + row16 + kt, lB1);
    __syncthreads();
    i32x4 af[4], bf[4];
    #pragma unroll
    for (int mi = 0; mi < 4; mi++) af[mi] = *(const i32x4*)(As + ((wm + (mi<<4) + fr) << 6) + fc);
    #pragma unroll
    for (int ni = 0; ni < 4; ni++) bf[ni] = *(const i32x4*)(Bs + ((wn + (ni<<4) + fr) << 6) + fc);
    #pragma unroll
    for (int mi = 0; mi < 4; mi++)
      #pragma unroll
      for (int ni = 0; ni < 4; ni++)
        acc[mi][ni] = __builtin_amdgcn_mfma_i32_16x16x64_i8(af[mi], bf[ni], acc[mi][ni], 0, 0, 0);
  }

  const int cr0 = m0 + wm + ((l >> 4) << 2);
  const int cc0 = n0 + wn + fr;
  #pragma unroll
  for (int mi = 0; mi < 4; mi++){
    float rf[4];
    #pragma unroll
    for (int j = 0; j < 4; j++) rf[j] = wsc / xs[cr0 + (mi<<4) + j];
    #pragma unroll
    for (int ni = 0; ni < 4; ni++){
      int col = cc0 + (ni<<4);
      #pragma unroll
      for (int j = 0; j < 4; j++){
        long row = cr0 + (mi<<4) + j;
        float vv = (float)acc[mi][ni][j] * rf[j];
        if (EPI == 0)      C[row*N + col] = vv;
        else if (EPI == 1) C[row*N + col] += vv;
        else               C[row*N + col] = gelu_f(vv);
      }
    }
  }
}

// ---------------- fp32 SGEMM: C = A[M,K] @ W[N,K]^T (+bias [+pos]) ----------------
template<int EPI>  // 0 = patch (bias+pos), 1 = head (bias)
__global__ __launch_bounds__(256) void k_sgemm(
  const float* __restrict__ A, const float* __restrict__ W,
  const float* __restrict__ bias, const float* __restrict__ pos,
  float* __restrict__ C, int N, int K)
{
  __shared__ float As[16][132];
  __shared__ float Bs[16][132];
  const int tid = threadIdx.x;
  const int tx = tid & 15, ty = tid >> 4;
  const int m0 = blockIdx.y << 7, n0 = blockIdx.x << 7;
  const int srow = tid >> 2, scol = (tid & 3) << 2;
  float acc[8][8] = {};
  const float* Ag0 = A + (long)(m0 + srow)*K + scol;
  const float* Ag1 = A + (long)(m0 + 64 + srow)*K + scol;
  const float* Bg0 = W + (long)(n0 + srow)*K + scol;
  const float* Bg1 = W + (long)(n0 + 64 + srow)*K + scol;

  for (int kt = 0; kt < K; kt += 16){
    float4 a0 = ld4(Ag0 + kt), a1 = ld4(Ag1 + kt);
    float4 b0 = ld4(Bg0 + kt), b1 = ld4(Bg1 + kt);
    __syncthreads();
    As[scol+0][srow] = a0.x; As[scol+1][srow] = a0.y; As[scol+2][srow] = a0.z; As[scol+3][srow] = a0.w;
    As[scol+0][64+srow] = a1.x; As[scol+1][64+srow] = a1.y; As[scol+2][64+srow] = a1.z; As[scol+3][64+srow] = a1.w;
    Bs[scol+0][srow] = b0.x; Bs[scol+1][srow] = b0.y; Bs[scol+2][srow] = b0.z; Bs[scol+3][srow] = b0.w;
    Bs[scol+0][64+srow] = b1.x; Bs[scol+1][64+srow] = b1.y; Bs[scol+2][64+srow] = b1.z; Bs[scol+3][64+srow] = b1.w;
    __syncthreads();
    #pragma unroll
    for (int k = 0; k < 16; k++){
      float a[8], b[8];
      *(float4*)&a[0] = *(const float4*)&As[k][ty*8];
      *(float4*)&a[4] = *(const float4*)&As[k][ty*8 + 4];
      *(float4*)&b[0] = *(const float4*)&Bs[k][tx*4];
      *(float4*)&b[4] = *(const float4*)&Bs[k][64 + tx*4];
      #pragma unroll
      for (int i = 0; i < 8; i++)
        #pragma unroll
        for (int j = 0; j < 8; j++)
          acc[i][j] = fmaf(a[i], b[j], acc[i][j]);
    }
  }

  #pragma unroll
  for (int i = 0; i < 8; i++){
    int row = m0 + ty*8 + i;
    float* cp = C + (long)row*N;
    #pragma unroll
    for (int half = 0; half < 2; half++){
      int c0 = n0 + half*64 + tx*4;
      float o[4];
      #pragma unroll
      for (int j = 0; j < 4; j++){
        o[j] = acc[i][half*4 + j] + bias[c0 + j];
        if (EPI == 0) o[j] += pos[(long)(row & 255)*768 + c0 + j];
      }
      *(float4*)(cp + c0) = *(float4*)o;
    }
  }
}

// ---------------- attention: per (b,h,qtile64), online softmax, fp32 ----------------
__global__ __launch_bounds__(256, 2) void k_attn(const float* __restrict__ QKV, float* __restrict__ O)
{
  __shared__ float Qs[64][68];
  __shared__ float Ks[64][68];   // column-XOR-swizzled by ((row>>4)<<2)
  __shared__ float Vs[64][68];
  __shared__ float Ps[64][68];
  const int tid = threadIdx.x;
  const int qt = blockIdx.x & 3;
  const int h  = (blockIdx.x >> 2) % NHEADS;
  const int b  = blockIdx.x / (4*NHEADS);
  const int r  = tid >> 2, c4 = tid & 3;
  const int wswz = (r >> 4) << 2;       // write-side swizzle (row group)
  const int rswz = c4 << 2;             // read-side swizzle (j>>4 == c4)

  {
    const float* qsrc = QKV + (long)((b << 8) + (qt << 6) + r)*2304 + (h << 6) + (c4 << 4);
    #pragma unroll
    for (int q = 0; q < 4; q++){
      float4 t = ld4(qsrc + q*4);
      t.x *= 0.125f; t.y *= 0.125f; t.z *= 0.125f; t.w *= 0.125f;
      *(float4*)&Qs[r][(c4 << 4) + q*4] = t;
    }
  }

  float4 oa[4];
  #pragma unroll
  for (int q = 0; q < 4; q++) oa[q] = make_float4(0.f, 0.f, 0.f, 0.f);
  float m_run = -3.0e38f, l_run = 0.f;
  const float* kbase = QKV + (long)((b << 8) + r)*2304 + 768 + (h << 6) + (c4 << 4);

  for (int kt = 0; kt < 4; ++kt){
    __syncthreads();
    const float* ksrc = kbase + (long)(kt << 6)*2304;
    #pragma unroll
    for (int q = 0; q < 4; q++){
      float4 kk = ld4(ksrc + q*4);
      *(float4*)&Ks[r][(((c4 << 4) + q*4) ^ wswz)] = kk;
      float4 vv = ld4(ksrc + 768 + q*4);
      *(float4*)&Vs[r][(c4 << 4) + q*4] = vv;
    }
    __syncthreads();

    float s[16];
    #pragma unroll
    for (int jj = 0; jj < 16; jj++) s[jj] = 0.f;
    const int jbase = c4 << 4;
    for (int d = 0; d < 64; d += 4){
      float4 q4 = *(const float4*)&Qs[r][d];
      #pragma unroll
      for (int jj = 0; jj < 16; jj++){
        float4 k4 = *(const float4*)&Ks[jbase + jj][d ^ rswz];
        s[jj] = fmaf(q4.x, k4.x, fmaf(q4.y, k4.y, fmaf(q4.z, k4.z, fmaf(q4.w, k4.w, s[jj]))));
      }
    }

    float mt = s[0];
    #pragma unroll
    for (int jj = 1; jj < 16; jj++) mt = fmaxf(mt, s[jj]);
    mt = fmaxf(mt, __shfl_xor(mt, 1));
    mt = fmaxf(mt, __shfl_xor(mt, 2));
    float m_new = fmaxf(m_run, mt);
    float alpha = __expf(m_run - m_new);
    float psum = 0.f;
    #pragma unroll
    for (int jj = 0; jj < 16; jj++){
      float p = __expf(s[jj] - m_new);
      psum += p;
      Ps[r][jbase + jj] = p;
    }
    psum += __shfl_xor(psum, 1);
    psum += __shfl_xor(psum, 2);
    l_run = l_run*alpha + psum;
    m_run = m_new;
    #pragma unroll
    for (int q = 0; q < 4; q++){
      oa[q].x *= alpha; oa[q].y *= alpha; oa[q].z *= alpha; oa[q].w *= alpha;
    }
    __syncthreads();
    #pragma unroll 4
    for (int kv = 0; kv < 64; ++kv){
      float p = Ps[r][kv];
      #pragma unroll
      for (int q = 0; q < 4; q++){
        float4 v4 = *(const float4*)&Vs[kv][(c4 << 4) + q*4];
        oa[q].x = fmaf(p, v4.x, oa[q].x);
        oa[q].y = fmaf(p, v4.y, oa[q].y);
        oa[q].z = fmaf(p, v4.z, oa[q].z);
        oa[q].w = fmaf(p, v4.w, oa[q].w);
      }
    }
  }

  float inv = 1.f / l_run;
  float* dst = O + (long)((b << 8) + (qt << 6) + r)*768 + (h << 6) + (c4 << 4);
  #pragma unroll
  for (int q = 0; q < 4; q++){
    float4 t = oa[q];
    t.x *= inv; t.y *= inv; t.z *= inv; t.w *= inv;
    *(float4*)(dst + q*4) = t;
  }
}

// ---------------- workspace layout ----------------
constexpr size_t WQ_OFF  = 0;                          // int8 quantized weights
constexpr size_t WQ_SZ   = 84934656ULL;                // 12 * 7,077,888
constexpr size_t ACC_OFF = WQ_OFF + WQ_SZ;
constexpr size_t WS_OFF  = ACC_OFF + 256;
constexpr size_t Z_OFF   = WS_OFF + 256;               // 4096x768 f32
constexpr size_t XP_OFF  = Z_OFF + 12582912ULL;        // 4096x768 f32 (patchified / normed)
constexpr size_t BIG_OFF = XP_OFF + 12582912ULL;       // 4096x3072 f32 (QKV / MLP-h / head-out)
constexpr size_t AO_OFF  = BIG_OFF + 50331648ULL;      // 4096x768 f32 attn out
constexpr size_t XQ_OFF  = AO_OFF + 12582912ULL;       // 4096x3072 int8
constexpr size_t XS_OFF  = XQ_OFF + 12582912ULL;       // 4096 f32
constexpr size_t TE_OFF  = XS_OFF + 16384;             // 16x768 f32
constexpr size_t SI_OFF  = TE_OFF + 49152;             // 16x768 f32
constexpr size_t MOD_OFF = SI_OFF + 49152;             // 12x16x3072 f32

extern "C" void kernel_launch(void* const* d_in, const int* in_sizes, int n_in,
                              void* d_out, int out_size, void* d_ws, size_t ws_size,
                              hipStream_t stream)
{
  (void)in_sizes; (void)n_in; (void)out_size; (void)ws_size;
  const float* x       = (const float*)d_in[0];
  const float* t       = (const float*)d_in[1];
  const float* patch_w = (const float*)d_in[2];
  const float* patch_b = (const float*)d_in[3];
  const float* pos     = (const float*)d_in[4];
  const float* t_w1    = (const float*)d_in[5];
  const float* t_b1    = (const float*)d_in[6];
  const float* t_w2    = (const float*)d_in[7];
  const float* t_b2    = (const float*)d_in[8];
  const float* n1      = (const float*)d_in[9];
  const float* wqkv    = (const float*)d_in[10];
  const float* wproj   = (const float*)d_in[11];
  const float* n2      = (const float*)d_in[12];
  const float* wfc1    = (const float*)d_in[13];
  const float* wfc2    = (const float*)d_in[14];
  const float* wada    = (const float*)d_in[15];
  const float* bada    = (const float*)d_in[16];
  const float* norm_w  = (const float*)d_in[17];
  const float* head_w  = (const float*)d_in[18];
  const float* head_b  = (const float*)d_in[19];
  float* out = (float*)d_out;

  char* ws = (char*)d_ws;
  signed char* WQ  = (signed char*)(ws + WQ_OFF);
  float* ACC = (float*)(ws + ACC_OFF);
  float* WSC = (float*)(ws + WS_OFF);
  float* Z   = (float*)(ws + Z_OFF);
  float* XP  = (float*)(ws + XP_OFF);
  float* BIG = (float*)(ws + BIG_OFF);
  float* AO  = (float*)(ws + AO_OFF);
  signed char* XQ = (signed char*)(ws + XQ_OFF);
  float* XS  = (float*)(ws + XS_OFF);
  float* TE  = (float*)(ws + TE_OFF);
  float* SI  = (float*)(ws + SI_OFF);
  float* MODP = (float*)(ws + MOD_OFF);

  // weight quantization
  hipMemsetAsync(ACC, 0, 48*sizeof(float), stream);
  dim3 gq(1152, 48);
  k_wabs_reduce<<<gq, 256, 0, stream>>>(wqkv, wproj, wfc1, wfc2, ACC);
  k_wscale<<<1, 64, 0, stream>>>(ACC, WSC);
  k_wquant_write<<<gq, 256, 0, stream>>>(wqkv, wproj, wfc1, wfc2, WSC, WQ);

  // patch embed + pos
  k_patchify<<<12288, 256, 0, stream>>>(x, XP);
  k_sgemm<0><<<dim3(6, 32), 256, 0, stream>>>(XP, patch_w, patch_b, pos, Z, 768, 768);

  // time embedding + per-layer modulation
  k_time_full<<<16, 256, 0, stream>>>(t, t_w1, t_b1, t_w2, t_b2, TE, SI);
  k_mod_all<<<dim3(12, 12), 256, 0, stream>>>(SI, wada, bada, MODP);

  for (int i = 0; i < 12; i++){
    const float* n1i  = n1 + i*768;
    const float* n2i  = n2 + i*768;
    const float* modi = MODP + (size_t)i*16*3072;
    const signed char* wq_qkv  = WQ + (size_t)i*7077888 + 0;
    const signed char* wq_proj = WQ + (size_t)i*7077888 + 1769472;
    const signed char* wq_fc1  = WQ + (size_t)i*7077888 + 2359296;
    const signed char* wq_fc2  = WQ + (size_t)i*7077888 + 4718592;
    const float* ws_i = WSC + i*4;

    k_rmsnorm_mod_quant<<<4096, 256, 0, stream>>>(Z, n1i, modi, 0, XQ, XS);
    k_gemm_i8<0><<<dim3(18, 32), 256, 0, stream>>>(XQ, wq_qkv, XS, ws_i + 0, BIG, 2304, 768);
    k_attn<<<768, 256, 0, stream>>>(BIG, AO);
    k_quant_rows<768><<<4096, 256, 0, stream>>>(AO, XQ, XS);
    k_gemm_i8<1><<<dim3(6, 32), 256, 0, stream>>>(XQ, wq_proj, XS, ws_i + 1, Z, 768, 768);
    k_rmsnorm_mod_quant<<<4096, 256, 0, stream>>>(Z, n2i, modi, 1536, XQ, XS);
    k_gemm_i8<2><<<dim3(24, 32), 256, 0, stream>>>(XQ, wq_fc1, XS, ws_i + 2, BIG, 3072, 768);
    k_quant_rows<3072><<<4096, 256, 0, stream>>>(BIG, XQ, XS);
    k_gemm_i8<1><<<dim3(6, 32), 256, 0, stream>>>(XQ, wq_fc2, XS, ws_i + 3, Z, 768, 3072);
  }

  // final norm + head + unpatchify
  k_rmsnorm_final<<<4096, 256, 0, stream>>>(Z, norm_w, XP);
  k_sgemm<1><<<dim3(6, 32), 256, 0, stream>>>(XP, head_w, head_b, nullptr, BIG, 768, 768);
  k_unpatchify<<<12288, 256, 0, stream>>>(BIG, out);
}

// Round 2
// 3612.415 us; speedup vs baseline: 1.0993x; 1.0993x over previous
//
#include <hip/hip_runtime.h>
#include <cstdint>

// ---------------- constants ----------------
#define NTOK   4096       // 16 imgs * 256 patches
#define CDIM   768
#define NHID   3072
#define NHEADS 12

typedef int i32x4 __attribute__((ext_vector_type(4)));

__device__ __forceinline__ float4 ld4(const float* p){ return *(const float4*)(p); }

__device__ __forceinline__ float gelu_f(float x){
  float x3 = x*x*x;
  return 0.5f*x*(1.0f + tanhf(0.7978845608028654f*(x + 0.044715f*x3)));
}

// ---------------- block-wide reduce (256 threads / 4 waves) ----------------
template<bool ISMAX>
__device__ __forceinline__ float block_reduce(float v, float* red){
  #pragma unroll
  for (int o = 32; o > 0; o >>= 1){
    float w = __shfl_down(v, o);
    v = ISMAX ? fmaxf(v, w) : (v + w);
  }
  int wid = threadIdx.x >> 6;
  if ((threadIdx.x & 63) == 0) red[wid] = v;
  __syncthreads();
  float r = ISMAX ? fmaxf(fmaxf(red[0], red[1]), fmaxf(red[2], red[3]))
                  : (red[0] + red[1] + red[2] + red[3]);
  __syncthreads();
  return r;
}

// ---------------- weight quantization ----------------
// 48 layers: layer = blk*4 + type; type 0=qkv(2304x768) 1=proj(768x768) 2=fc1(3072x768) 3=fc2(768x3072)
__device__ __forceinline__ const float* layer_base(int type, int blk,
    const float* wqkv, const float* wproj, const float* wfc1, const float* wfc2,
    long* n_out, long* qoff_out)
{
  switch (type){
    case 0:  *n_out = 2304L*768; *qoff_out = 0;       return wqkv  + (long)blk*2304*768;
    case 1:  *n_out = 768L*768;  *qoff_out = 1769472; return wproj + (long)blk*768*768;
    case 2:  *n_out = 3072L*768; *qoff_out = 2359296; return wfc1  + (long)blk*3072*768;
    default: *n_out = 768L*3072; *qoff_out = 4718592; return wfc2  + (long)blk*768*3072;
  }
}

// grid (72, 48): grid-stride per layer; ONE atomic per block (48-72 per address,
// not 1152 -> kills the same-address atomic serialization seen in round 1)
__global__ __launch_bounds__(256) void k_wabs_reduce(
  const float* __restrict__ wqkv, const float* __restrict__ wproj,
  const float* __restrict__ wfc1, const float* __restrict__ wfc2,
  float* __restrict__ acc)
{
  __shared__ float red[4];
  int layer = blockIdx.y, blk = layer >> 2, type = layer & 3;
  long n, qoff;
  const float* base = layer_base(type, blk, wqkv, wproj, wfc1, wfc2, &n, &qoff);
  float s = 0.f;
  const long stride = 72L*256*8;
  for (long i0 = ((long)blockIdx.x*256 + threadIdx.x)*8; i0 < n; i0 += stride){
    float4 a = ld4(base+i0), b = ld4(base+i0+4);
    s += fabsf(a.x)+fabsf(a.y)+fabsf(a.z)+fabsf(a.w)
       + fabsf(b.x)+fabsf(b.y)+fabsf(b.z)+fabsf(b.w);
  }
  s = block_reduce<false>(s, red);
  if (threadIdx.x == 0) atomicAdd(&acc[layer], s);
}

__global__ void k_wscale(const float* __restrict__ acc, float* __restrict__ wsc){
  int l = threadIdx.x;
  if (l < 48){
    const float cnt[4] = {2304.f*768.f, 768.f*768.f, 3072.f*768.f, 768.f*3072.f};
    wsc[l] = acc[l]/cnt[l & 3] + 1e-5f;
  }
}

// grid (36, 48): grid-stride, 16 elems/thread, 16B packed store
__global__ __launch_bounds__(256) void k_wquant_write(
  const float* __restrict__ wqkv, const float* __restrict__ wproj,
  const float* __restrict__ wfc1, const float* __restrict__ wfc2,
  const float* __restrict__ wsc, signed char* __restrict__ wq)
{
  int layer = blockIdx.y, blk = layer >> 2, type = layer & 3;
  long n, qoff;
  const float* base = layer_base(type, blk, wqkv, wproj, wfc1, wfc2, &n, &qoff);
  signed char* dst = wq + (long)blk*7077888 + qoff;
  float ws = wsc[layer];
  const long stride = 36L*256*16;
  for (long i0 = ((long)blockIdx.x*256 + threadIdx.x)*16; i0 < n; i0 += stride){
    float v[16];
    *(float4*)&v[0]  = ld4(base+i0);
    *(float4*)&v[4]  = ld4(base+i0+4);
    *(float4*)&v[8]  = ld4(base+i0+8);
    *(float4*)&v[12] = ld4(base+i0+12);
    i32x4 pk;
    char* pc = (char*)&pk;
    #pragma unroll
    for (int e = 0; e < 16; e++){
      float r = rintf(v[e] / ws);            // precise div + round-half-even == jnp.round
      r = fminf(1.f, fmaxf(-1.f, r));
      pc[e] = (char)(int)r;
    }
    *(i32x4*)(dst + i0) = pk;
  }
}

// ---------------- patchify / unpatchify ----------------
__global__ __launch_bounds__(256) void k_patchify(const float* __restrict__ x, float* __restrict__ xp){
  int idx = blockIdx.x*256 + threadIdx.x;   // over 4096*768
  int col = idx % 768, row = idx / 768;
  int bb = row >> 8, pr = row & 255, ph = pr >> 4, pw = pr & 15;
  int c = col >> 8, rem = col & 255, ii = rem >> 4, jj = rem & 15;
  xp[idx] = x[(((long)(bb*3 + c) << 8) + (ph<<4) + ii)*256 + (pw<<4) + jj];
}

__global__ __launch_bounds__(256) void k_unpatchify(const float* __restrict__ H, float* __restrict__ out){
  int idx = blockIdx.x*256 + threadIdx.x;   // over 16*3*256*256
  int xc = idx & 255;
  int y  = (idx >> 8) & 255;
  int bc = idx >> 16;
  int bb = bc / 3, c = bc % 3;
  int row = (bb << 8) + ((y >> 4) << 4) + (xc >> 4);
  int col = (c << 8) + ((y & 15) << 4) + (xc & 15);
  out[idx] = H[(long)row*768 + col];
}

// ---------------- time embedding (tiny) ----------------
__global__ __launch_bounds__(256) void k_time_full(
  const float* __restrict__ tt, const float* __restrict__ w1, const float* __restrict__ b1,
  const float* __restrict__ w2, const float* __restrict__ b2,
  float* __restrict__ silu)
{
  __shared__ float emb[768];
  __shared__ float h1[768];
  int b = blockIdx.x, tid = threadIdx.x;
  float tv = tt[b];
  for (int i = tid; i < 768; i += 256){
    int idx = (i < 384) ? i : (i - 384);
    float fr = expf(-9.210340371976184f * (float)idx / 383.f);
    float a = tv * fr;
    emb[i] = (i < 384) ? sinf(a) : cosf(a);
  }
  __syncthreads();
  for (int o = tid; o < 768; o += 256){
    const float* wr = w1 + (long)o*768;
    float s = b1[o];
    for (int d = 0; d < 768; d += 4){
      float4 w4 = ld4(wr+d);
      s += w4.x*emb[d] + w4.y*emb[d+1] + w4.z*emb[d+2] + w4.w*emb[d+3];
    }
    h1[o] = gelu_f(s);
  }
  __syncthreads();
  for (int o = tid; o < 768; o += 256){
    const float* wr = w2 + (long)o*768;
    float s = b2[o];
    for (int d = 0; d < 768; d += 4){
      float4 w4 = ld4(wr+d);
      s += w4.x*h1[d] + w4.y*h1[d+1] + w4.z*h1[d+2] + w4.w*h1[d+3];
    }
    float te = s;
    silu[b*768 + o] = te / (1.f + expf(-te));
  }
}

// ---------------- adaLN modulation for all layers ----------------
// grid (chunk 0..11, layer 0..11); mod[l][b][r] = silu(temb[b]) . ada_w[l][r] + ada_b[l][r]
__global__ __launch_bounds__(256) void k_mod_all(
  const float* __restrict__ silu, const float* __restrict__ wada, const float* __restrict__ bada,
  float* __restrict__ mod)
{
  __shared__ float ss[12288];     // 16 x 768
  int l = blockIdx.y, ch = blockIdx.x, tid = threadIdx.x;
  for (int i = tid; i < 12288; i += 256) ss[i] = silu[i];
  __syncthreads();
  int r = (ch << 8) + tid;
  const float* wr = wada + ((long)l*3072 + r)*768;
  float accv[16];
  #pragma unroll
  for (int b2 = 0; b2 < 16; b2++) accv[b2] = 0.f;
  for (int d = 0; d < 768; d += 4){
    float4 w4 = ld4(wr+d);
    #pragma unroll
    for (int b2 = 0; b2 < 16; b2++){
      float4 s4 = *(const float4*)&ss[b2*768 + d];
      accv[b2] += w4.x*s4.x + w4.y*s4.y + w4.z*s4.z + w4.w*s4.w;
    }
  }
  float bb = bada[(long)l*3072 + r];
  #pragma unroll
  for (int b2 = 0; b2 < 16; b2++)
    mod[((long)l*16 + b2)*3072 + r] = accv[b2] + bb;
}

// ---------------- rmsnorm + modulate + int8 quantize ----------------
// mod_off: 0 for (shift1,scale1), 1536 for (shift2,scale2)
__global__ __launch_bounds__(256) void k_rmsnorm_mod_quant(
  const float* __restrict__ Z, const float* __restrict__ nw,
  const float* __restrict__ mod, int mod_off,
  signed char* __restrict__ XQ, float* __restrict__ XS)
{
  __shared__ float red[4];
  int row = blockIdx.x, tid = threadIdx.x;
  int b = row >> 8;
  const float* zr = Z + (long)row*768;
  const float* mo = mod + (long)b*3072 + mod_off;
  float v[3]; float ss = 0.f;
  #pragma unroll
  for (int k = 0; k < 3; k++){ v[k] = zr[tid + k*256]; ss += v[k]*v[k]; }
  ss = block_reduce<false>(ss, red);
  float rms = rsqrtf(ss*(1.f/768.f) + 1e-6f);
  float h[3]; float amax = 0.f;
  #pragma unroll
  for (int k = 0; k < 3; k++){
    int c = tid + k*256;
    h[k] = v[k]*rms*nw[c]*(1.f + mo[768 + c]) + mo[c];
    amax = fmaxf(amax, fabsf(h[k]));
  }
  amax = block_reduce<true>(amax, red);
  float xs = 127.f / fmaxf(amax, 1e-5f);
  #pragma unroll
  for (int k = 0; k < 3; k++){
    int q = (int)rintf(h[k]*xs);
    q = min(127, max(-128, q));
    XQ[(long)row*768 + tid + k*256] = (signed char)q;
  }
  if (tid == 0) XS[row] = xs;
}

// ---------------- plain row quantize (attn-out 768 / mlp 3072) ----------------
template<int W>
__global__ __launch_bounds__(256) void k_quant_rows(
  const float* __restrict__ X, signed char* __restrict__ XQ, float* __restrict__ XS)
{
  __shared__ float red[4];
  int row = blockIdx.x, tid = threadIdx.x;
  const float* xr = X + (long)row*W;
  constexpr int E = W/256;
  float v[E]; float amax = 0.f;
  #pragma unroll
  for (int k = 0; k < E; k++){ v[k] = xr[tid + k*256]; amax = fmaxf(amax, fabsf(v[k])); }
  amax = block_reduce<true>(amax, red);
  float xs = 127.f / fmaxf(amax, 1e-5f);
  #pragma unroll
  for (int k = 0; k < E; k++){
    int q = (int)rintf(v[k]*xs);
    q = min(127, max(-128, q));
    XQ[(long)row*W + tid + k*256] = (signed char)q;
  }
  if (tid == 0) XS[row] = xs;
}

__global__ __launch_bounds__(256) void k_rmsnorm_final(
  const float* __restrict__ Z, const float* __restrict__ nw, float* __restrict__ Y)
{
  __shared__ float red[4];
  int row = blockIdx.x, tid = threadIdx.x;
  const float* zr = Z + (long)row*768;
  float v[3]; float ss = 0.f;
  #pragma unroll
  for (int k = 0; k < 3; k++){ v[k] = zr[tid + k*256]; ss += v[k]*v[k]; }
  ss = block_reduce<false>(ss, red);
  float rms = rsqrtf(ss*(1.f/768.f) + 1e-6f);
  #pragma unroll
  for (int k = 0; k < 3; k++){
    int c = tid + k*256;
    Y[(long)row*768 + c] = v[k]*rms*nw[c];
  }
}

// ---------------- int8 x ternary GEMM via MFMA (m97 structure) ----------------
// C[M,N] = (A[M,K]i8 @ B[N,K]i8^T) * wsc / xs[row];  128x128 tile, BK=64, 4 waves
// NSPLIT>1: split-K over blockIdx.z; epilogue EPI==1 uses atomicAdd (f32, exact int acc)
#define GLDS16(g, l) __builtin_amdgcn_global_load_lds( \
    (const __attribute__((address_space(1))) void*)(g), \
    (__attribute__((address_space(3))) void*)(l), 16, 0, 0)

template<int EPI, int NSPLIT>  // EPI: 0=store, 1=residual-add, 2=gelu-store
__global__ __launch_bounds__(256, 2) void k_gemm_i8(
  const signed char* __restrict__ A, const signed char* __restrict__ Bw,
  const float* __restrict__ xs, const float* __restrict__ wsc_p,
  float* __restrict__ C, int N, int K)
{
  __shared__ signed char As[8192];
  __shared__ signed char Bs[8192];
  const int tid = threadIdx.x;
  const int w = tid >> 6, l = tid & 63;
  const int m0 = blockIdx.y << 7, n0 = blockIdx.x << 7;
  const float wsc = wsc_p[0];
  i32x4 acc[4][4] = {};
  const int srow = (w << 5) + (l >> 2);
  const int scol = (l & 3) << 4;
  const signed char* Ag0 = A  + (long)(m0 + srow)*K + scol;
  const signed char* Bg0 = Bw + (long)(n0 + srow)*K + scol;
  const long row16 = 16L*K;
  signed char* lA0 = As + (w << 11);
  signed char* lA1 = lA0 + 1024;
  signed char* lB0 = Bs + (w << 11);
  signed char* lB1 = lB0 + 1024;
  const int fr = l & 15;
  const int fc = (l >> 4) << 4;
  const int wm = (w >> 1) << 6, wn = (w & 1) << 6;

  const int Ksp = K / NSPLIT;
  const int k_begin = (NSPLIT > 1) ? (int)blockIdx.z * Ksp : 0;
  const int k_end = k_begin + Ksp;

  for (int kt = k_begin; kt < k_end; kt += 64){
    __syncthreads();
    GLDS16(Ag0 + kt, lA0);
    GLDS16(Ag0 + row16 + kt, lA1);
    GLDS16(Bg0 + kt, lB0);
    GLDS16(Bg0 + row16 + kt, lB1);
    __syncthreads();
    i32x4 af[4], bf[4];
    #pragma unroll
    for (int mi = 0; mi < 4; mi++) af[mi] = *(const i32x4*)(As + ((wm + (mi<<4) + fr) << 6) + fc);
    #pragma unroll
    for (int ni = 0; ni < 4; ni++) bf[ni] = *(const i32x4*)(Bs + ((wn + (ni<<4) + fr) << 6) + fc);
    #pragma unroll
    for (int mi = 0; mi < 4; mi++)
      #pragma unroll
      for (int ni = 0; ni < 4; ni++)
        acc[mi][ni] = __builtin_amdgcn_mfma_i32_16x16x64_i8(af[mi], bf[ni], acc[mi][ni], 0, 0, 0);
  }

  const int cr0 = m0 + wm + ((l >> 4) << 2);
  const int cc0 = n0 + wn + fr;
  #pragma unroll
  for (int mi = 0; mi < 4; mi++){
    float rf[4];
    #pragma unroll
    for (int j = 0; j < 4; j++) rf[j] = wsc / xs[cr0 + (mi<<4) + j];
    #pragma unroll
    for (int ni = 0; ni < 4; ni++){
      int col = cc0 + (ni<<4);
      #pragma unroll
      for (int j = 0; j < 4; j++){
        long row = cr0 + (mi<<4) + j;
        float vv = (float)acc[mi][ni][j] * rf[j];
        if (EPI == 0)      C[row*N + col] = vv;
        else if (EPI == 1){
          if (NSPLIT > 1)  atomicAdd(&C[row*N + col], vv);
          else             C[row*N + col] += vv;
        }
        else               C[row*N + col] = gelu_f(vv);
      }
    }
  }
}

// ---------------- fp32 SGEMM: C = A[M,K] @ W[N,K]^T (+bias [+pos]) ----------------
template<int EPI>  // 0 = patch (bias+pos), 1 = head (bias)
__global__ __launch_bounds__(256) void k_sgemm(
  const float* __restrict__ A, const float* __restrict__ W,
  const float* __restrict__ bias, const float* __restrict__ pos,
  float* __restrict__ C, int N, int K)
{
  __shared__ float As[16][132];
  __shared__ float Bs[16][132];
  const int tid = threadIdx.x;
  const int tx = tid & 15, ty = tid >> 4;
  const int m0 = blockIdx.y << 7, n0 = blockIdx.x << 7;
  const int srow = tid >> 2, scol = (tid & 3) << 2;
  float acc[8][8] = {};
  const float* Ag0 = A + (long)(m0 + srow)*K + scol;
  const float* Ag1 = A + (long)(m0 + 64 + srow)*K + scol;
  const float* Bg0 = W + (long)(n0 + srow)*K + scol;
  const float* Bg1 = W + (long)(n0 + 64 + srow)*K + scol;

  for (int kt = 0; kt < K; kt += 16){
    float4 a0 = ld4(Ag0 + kt), a1 = ld4(Ag1 + kt);
    float4 b0 = ld4(Bg0 + kt), b1 = ld4(Bg1 + kt);
    __syncthreads();
    As[scol+0][srow] = a0.x; As[scol+1][srow] = a0.y; As[scol+2][srow] = a0.z; As[scol+3][srow] = a0.w;
    As[scol+0][64+srow] = a1.x; As[scol+1][64+srow] = a1.y; As[scol+2][64+srow] = a1.z; As[scol+3][64+srow] = a1.w;
    Bs[scol+0][srow] = b0.x; Bs[scol+1][srow] = b0.y; Bs[scol+2][srow] = b0.z; Bs[scol+3][srow] = b0.w;
    Bs[scol+0][64+srow] = b1.x; Bs[scol+1][64+srow] = b1.y; Bs[scol+2][64+srow] = b1.z; Bs[scol+3][64+srow] = b1.w;
    __syncthreads();
    #pragma unroll
    for (int k = 0; k < 16; k++){
      float a[8], b[8];
      *(float4*)&a[0] = *(const float4*)&As[k][ty*8];
      *(float4*)&a[4] = *(const float4*)&As[k][ty*8 + 4];
      *(float4*)&b[0] = *(const float4*)&Bs[k][tx*4];
      *(float4*)&b[4] = *(const float4*)&Bs[k][64 + tx*4];
      #pragma unroll
      for (int i = 0; i < 8; i++)
        #pragma unroll
        for (int j = 0; j < 8; j++)
          acc[i][j] = fmaf(a[i], b[j], acc[i][j]);
    }
  }

  #pragma unroll
  for (int i = 0; i < 8; i++){
    int row = m0 + ty*8 + i;
    float* cp = C + (long)row*N;
    #pragma unroll
    for (int half = 0; half < 2; half++){
      int c0 = n0 + half*64 + tx*4;
      float o[4];
      #pragma unroll
      for (int j = 0; j < 4; j++){
        o[j] = acc[i][half*4 + j] + bias[c0 + j];
        if (EPI == 0) o[j] += pos[(long)(row & 255)*768 + c0 + j];
      }
      *(float4*)(cp + c0) = *(float4*)o;
    }
  }
}

// ---------------- attention: per (b,h,qtile64), online softmax, fp32 ----------------
__global__ __launch_bounds__(256, 2) void k_attn(const float* __restrict__ QKV, float* __restrict__ O)
{
  __shared__ float Qs[64][68];
  __shared__ float Ks[64][68];   // column-XOR-swizzled by ((row>>4)<<2)
  __shared__ float Vs[64][68];
  __shared__ float Ps[64][68];
  const int tid = threadIdx.x;
  const int qt = blockIdx.x & 3;
  const int h  = (blockIdx.x >> 2) % NHEADS;
  const int b  = blockIdx.x / (4*NHEADS);
  const int r  = tid >> 2, c4 = tid & 3;
  const int wswz = (r >> 4) << 2;       // write-side swizzle (row group)
  const int rswz = c4 << 2;             // read-side swizzle (j>>4 == c4)

  {
    const float* qsrc = QKV + (long)((b << 8) + (qt << 6) + r)*2304 + (h << 6) + (c4 << 4);
    #pragma unroll
    for (int q = 0; q < 4; q++){
      float4 t = ld4(qsrc + q*4);
      t.x *= 0.125f; t.y *= 0.125f; t.z *= 0.125f; t.w *= 0.125f;
      *(float4*)&Qs[r][(c4 << 4) + q*4] = t;
    }
  }

  float4 oa[4];
  #pragma unroll
  for (int q = 0; q < 4; q++) oa[q] = make_float4(0.f, 0.f, 0.f, 0.f);
  float m_run = -3.0e38f, l_run = 0.f;
  const float* kbase = QKV + (long)((b << 8) + r)*2304 + 768 + (h << 6) + (c4 << 4);

  for (int kt = 0; kt < 4; ++kt){
    __syncthreads();
    const float* ksrc = kbase + (long)(kt << 6)*2304;
    #pragma unroll
    for (int q = 0; q < 4; q++){
      float4 kk = ld4(ksrc + q*4);
      *(float4*)&Ks[r][(((c4 << 4) + q*4) ^ wswz)] = kk;
      float4 vv = ld4(ksrc + 768 + q*4);
      *(float4*)&Vs[r][(c4 << 4) + q*4] = vv;
    }
    __syncthreads();

    float s[16];
    #pragma unroll
    for (int jj = 0; jj < 16; jj++) s[jj] = 0.f;
    const int jbase = c4 << 4;
    for (int d = 0; d < 64; d += 4){
      float4 q4 = *(const float4*)&Qs[r][d];
      #pragma unroll
      for (int jj = 0; jj < 16; jj++){
        float4 k4 = *(const float4*)&Ks[jbase + jj][d ^ rswz];
        s[jj] = fmaf(q4.x, k4.x, fmaf(q4.y, k4.y, fmaf(q4.z, k4.z, fmaf(q4.w, k4.w, s[jj]))));
      }
    }

    float mt = s[0];
    #pragma unroll
    for (int jj = 1; jj < 16; jj++) mt = fmaxf(mt, s[jj]);
    mt = fmaxf(mt, __shfl_xor(mt, 1));
    mt = fmaxf(mt, __shfl_xor(mt, 2));
    float m_new = fmaxf(m_run, mt);
    float alpha = __expf(m_run - m_new);
    float psum = 0.f;
    #pragma unroll
    for (int jj = 0; jj < 16; jj++){
      float p = __expf(s[jj] - m_new);
      psum += p;
      Ps[r][jbase + jj] = p;
    }
    psum += __shfl_xor(psum, 1);
    psum += __shfl_xor(psum, 2);
    l_run = l_run*alpha + psum;
    m_run = m_new;
    #pragma unroll
    for (int q = 0; q < 4; q++){
      oa[q].x *= alpha; oa[q].y *= alpha; oa[q].z *= alpha; oa[q].w *= alpha;
    }
    __syncthreads();
    #pragma unroll 4
    for (int kv = 0; kv < 64; ++kv){
      float p = Ps[r][kv];
      #pragma unroll
      for (int q = 0; q < 4; q++){
        float4 v4 = *(const float4*)&Vs[kv][(c4 << 4) + q*4];
        oa[q].x = fmaf(p, v4.x, oa[q].x);
        oa[q].y = fmaf(p, v4.y, oa[q].y);
        oa[q].z = fmaf(p, v4.z, oa[q].z);
        oa[q].w = fmaf(p, v4.w, oa[q].w);
      }
    }
  }

  float inv = 1.f / l_run;
  float* dst = O + (long)((b << 8) + (qt << 6) + r)*768 + (h << 6) + (c4 << 4);
  #pragma unroll
  for (int q = 0; q < 4; q++){
    float4 t = oa[q];
    t.x *= inv; t.y *= inv; t.z *= inv; t.w *= inv;
    *(float4*)(dst + q*4) = t;
  }
}

// ---------------- workspace layout ----------------
constexpr size_t WQ_OFF  = 0;                          // int8 quantized weights
constexpr size_t WQ_SZ   = 84934656ULL;                // 12 * 7,077,888
constexpr size_t ACC_OFF = WQ_OFF + WQ_SZ;
constexpr size_t WS_OFF  = ACC_OFF + 256;
constexpr size_t Z_OFF   = WS_OFF + 256;               // 4096x768 f32
constexpr size_t XP_OFF  = Z_OFF + 12582912ULL;        // 4096x768 f32 (patchified / normed)
constexpr size_t BIG_OFF = XP_OFF + 12582912ULL;       // 4096x3072 f32 (QKV / MLP-h / head-out)
constexpr size_t AO_OFF  = BIG_OFF + 50331648ULL;      // 4096x768 f32 attn out
constexpr size_t XQ_OFF  = AO_OFF + 12582912ULL;       // 4096x3072 int8
constexpr size_t XS_OFF  = XQ_OFF + 12582912ULL;       // 4096 f32
constexpr size_t SI_OFF  = XS_OFF + 16384;             // 16x768 f32
constexpr size_t MOD_OFF = SI_OFF + 49152;             // 12x16x3072 f32

extern "C" void kernel_launch(void* const* d_in, const int* in_sizes, int n_in,
                              void* d_out, int out_size, void* d_ws, size_t ws_size,
                              hipStream_t stream)
{
  (void)in_sizes; (void)n_in; (void)out_size; (void)ws_size;
  const float* x       = (const float*)d_in[0];
  const float* t       = (const float*)d_in[1];
  const float* patch_w = (const float*)d_in[2];
  const float* patch_b = (const float*)d_in[3];
  const float* pos     = (const float*)d_in[4];
  const float* t_w1    = (const float*)d_in[5];
  const float* t_b1    = (const float*)d_in[6];
  const float* t_w2    = (const float*)d_in[7];
  const float* t_b2    = (const float*)d_in[8];
  const float* n1      = (const float*)d_in[9];
  const float* wqkv    = (const float*)d_in[10];
  const float* wproj   = (const float*)d_in[11];
  const float* n2      = (const float*)d_in[12];
  const float* wfc1    = (const float*)d_in[13];
  const float* wfc2    = (const float*)d_in[14];
  const float* wada    = (const float*)d_in[15];
  const float* bada    = (const float*)d_in[16];
  const float* norm_w  = (const float*)d_in[17];
  const float* head_w  = (const float*)d_in[18];
  const float* head_b  = (const float*)d_in[19];
  float* out = (float*)d_out;

  char* ws = (char*)d_ws;
  signed char* WQ  = (signed char*)(ws + WQ_OFF);
  float* ACC = (float*)(ws + ACC_OFF);
  float* WSC = (float*)(ws + WS_OFF);
  float* Z   = (float*)(ws + Z_OFF);
  float* XP  = (float*)(ws + XP_OFF);
  float* BIG = (float*)(ws + BIG_OFF);
  float* AO  = (float*)(ws + AO_OFF);
  signed char* XQ = (signed char*)(ws + XQ_OFF);
  float* XS  = (float*)(ws + XS_OFF);
  float* SI  = (float*)(ws + SI_OFF);
  float* MODP = (float*)(ws + MOD_OFF);

  // weight quantization
  hipMemsetAsync(ACC, 0, 48*sizeof(float), stream);
  k_wabs_reduce<<<dim3(72, 48), 256, 0, stream>>>(wqkv, wproj, wfc1, wfc2, ACC);
  k_wscale<<<1, 64, 0, stream>>>(ACC, WSC);
  k_wquant_write<<<dim3(36, 48), 256, 0, stream>>>(wqkv, wproj, wfc1, wfc2, WSC, WQ);

  // patch embed + pos
  k_patchify<<<12288, 256, 0, stream>>>(x, XP);
  k_sgemm<0><<<dim3(6, 32), 256, 0, stream>>>(XP, patch_w, patch_b, pos, Z, 768, 768);

  // time embedding + per-layer modulation
  k_time_full<<<16, 256, 0, stream>>>(t, t_w1, t_b1, t_w2, t_b2, SI);
  k_mod_all<<<dim3(12, 12), 256, 0, stream>>>(SI, wada, bada, MODP);

  for (int i = 0; i < 12; i++){
    const float* n1i  = n1 + i*768;
    const float* n2i  = n2 + i*768;
    const float* modi = MODP + (size_t)i*16*3072;
    const signed char* wq_qkv  = WQ + (size_t)i*7077888 + 0;
    const signed char* wq_proj = WQ + (size_t)i*7077888 + 1769472;
    const signed char* wq_fc1  = WQ + (size_t)i*7077888 + 2359296;
    const signed char* wq_fc2  = WQ + (size_t)i*7077888 + 4718592;
    const float* ws_i = WSC + i*4;

    k_rmsnorm_mod_quant<<<4096, 256, 0, stream>>>(Z, n1i, modi, 0, XQ, XS);
    k_gemm_i8<0,1><<<dim3(18, 32), 256, 0, stream>>>(XQ, wq_qkv, XS, ws_i + 0, BIG, 2304, 768);
    k_attn<<<768, 256, 0, stream>>>(BIG, AO);
    k_quant_rows<768><<<4096, 256, 0, stream>>>(AO, XQ, XS);
    k_gemm_i8<1,2><<<dim3(6, 32, 2), 256, 0, stream>>>(XQ, wq_proj, XS, ws_i + 1, Z, 768, 768);
    k_rmsnorm_mod_quant<<<4096, 256, 0, stream>>>(Z, n2i, modi, 1536, XQ, XS);
    k_gemm_i8<2,1><<<dim3(24, 32), 256, 0, stream>>>(XQ, wq_fc1, XS, ws_i + 2, BIG, 3072, 768);
    k_quant_rows<3072><<<4096, 256, 0, stream>>>(BIG, XQ, XS);
    k_gemm_i8<1,2><<<dim3(6, 32, 2), 256, 0, stream>>>(XQ, wq_fc2, XS, ws_i + 3, Z, 768, 3072);
  }

  // final norm + head + unpatchify
  k_rmsnorm_final<<<4096, 256, 0, stream>>>(Z, norm_w, XP);
  k_sgemm<1><<<dim3(6, 32), 256, 0, stream>>>(XP, head_w, head_b, nullptr, BIG, 768, 768);
  k_unpatchify<<<12288, 256, 0, stream>>>(BIG, out);
}